// Round 14
// baseline (102.486 us; speedup 1.0000x reference)
//
#include <hip/hip_runtime.h>

#define D_MODEL 256
#define TX 512
#define TM 512

__device__ __forceinline__ float fexp2(float x) { return __builtin_amdgcn_exp2f(x); }
__device__ __forceinline__ float frcp(float x)  { return __builtin_amdgcn_rcpf(x); }

// acc += sum_{i=0..3} w[i]/(1+a[i]*e[i])  with ONE v_rcp_f32 (exact algebra).
__device__ __forceinline__ float quad(float4 a, float4 e, float4 w, float acc) {
    float p1 = fmaf(a.x, e.x, 1.f);
    float p2 = fmaf(a.y, e.y, 1.f);
    float p3 = fmaf(a.z, e.z, 1.f);
    float p4 = fmaf(a.w, e.w, 1.f);
    float p12 = p1 * p2;
    float p34 = p3 * p4;
    float q12 = fmaf(w.x, p2, w.y * p1);
    float q34 = fmaf(w.z, p4, w.w * p3);
    float N   = fmaf(q12, p34, q34 * p12);
    float D   = p12 * p34;
    return fmaf(N, frcp(D), acc);
}

// Two NT-GEMMs; 32x64 tiles, 128-thread blocks, double-buffered LDS.
//  z=0: E1 [2048][256] = exp2(c*(x · w1^T + b1));  bid -> r0=(bid&63)*32, n0=(bid>>6)*64
//  z=1: E2p packed     = exp2(c*(w2 · mem^T));     bid -> r0=(bid&7)*32,  n0=(bid>>3)*64
// Grid (256, 1, 2), block 128.
__global__ __launch_bounds__(128) void gemm_exp2(
    const float* __restrict__ x,   const float* __restrict__ mem,
    const float* __restrict__ w1,  const float* __restrict__ b1,
    const float* __restrict__ w2,
    float* __restrict__ E1, float* __restrict__ E2p)
{
    const float C_SCALE = 2.8853900817779268f; // 2*log2(e)
    const int bid = (int)blockIdx.x;
    const float* A; const float* W;
    int r0, n0;
    if (blockIdx.z == 0) { A = x;  W = w1; r0 = (bid & 63) * 32; n0 = (bid >> 6) * 64; }
    else                 { A = w2; W = mem; r0 = (bid & 7) * 32;  n0 = (bid >> 3) * 64; }

    __shared__ float As[2][16][36];
    __shared__ float Ws[2][16][68];
    const int tid = threadIdx.x;
    const int tx = tid & 15, ty = tid >> 4;     // 16 col-groups x 8 row-groups
    const int rl = tid >> 2, g = tid & 3;       // staging: 32 rows x 4 k-groups
    float acc[4][4] = {};
    const float* Ap  = A + (size_t)(r0 + rl) * 256 + g * 4;
    const float* Wp0 = W + (size_t)(n0 + rl) * 256 + g * 4;
    const float* Wp1 = W + (size_t)(n0 + 32 + rl) * 256 + g * 4;

    {   // prologue: stage k0 = 0 into buffer 0
        float4 a4 = *(const float4*)Ap;
        float4 w4 = *(const float4*)Wp0;
        float4 w5 = *(const float4*)Wp1;
        As[0][g*4+0][rl] = a4.x; As[0][g*4+1][rl] = a4.y;
        As[0][g*4+2][rl] = a4.z; As[0][g*4+3][rl] = a4.w;
        Ws[0][g*4+0][rl] = w4.x; Ws[0][g*4+1][rl] = w4.y;
        Ws[0][g*4+2][rl] = w4.z; Ws[0][g*4+3][rl] = w4.w;
        Ws[0][g*4+0][rl+32] = w5.x; Ws[0][g*4+1][rl+32] = w5.y;
        Ws[0][g*4+2][rl+32] = w5.z; Ws[0][g*4+3][rl+32] = w5.w;
    }
    __syncthreads();

    for (int k0 = 0; k0 < 16; ++k0) {
        const int cur = k0 & 1;
        float4 an, wn, vn;
        if (k0 < 15) {
            an = *(const float4*)(Ap  + (k0 + 1) * 16);
            wn = *(const float4*)(Wp0 + (k0 + 1) * 16);
            vn = *(const float4*)(Wp1 + (k0 + 1) * 16);
        }
        #pragma unroll
        for (int kk = 0; kk < 16; ++kk) {
            float4 av = *(const float4*)&As[cur][kk][ty*4];
            float4 wv = *(const float4*)&Ws[cur][kk][tx*4];
            float a_[4] = {av.x, av.y, av.z, av.w};
            float w_[4] = {wv.x, wv.y, wv.z, wv.w};
            #pragma unroll
            for (int i = 0; i < 4; ++i)
                #pragma unroll
                for (int j = 0; j < 4; ++j)
                    acc[i][j] = fmaf(a_[i], w_[j], acc[i][j]);
        }
        if (k0 < 15) {
            const int nxt = cur ^ 1;
            As[nxt][g*4+0][rl] = an.x; As[nxt][g*4+1][rl] = an.y;
            As[nxt][g*4+2][rl] = an.z; As[nxt][g*4+3][rl] = an.w;
            Ws[nxt][g*4+0][rl] = wn.x; Ws[nxt][g*4+1][rl] = wn.y;
            Ws[nxt][g*4+2][rl] = wn.z; Ws[nxt][g*4+3][rl] = wn.w;
            Ws[nxt][g*4+0][rl+32] = vn.x; Ws[nxt][g*4+1][rl+32] = vn.y;
            Ws[nxt][g*4+2][rl+32] = vn.z; Ws[nxt][g*4+3][rl+32] = vn.w;
            __syncthreads();
        }
    }

    if (blockIdx.z == 0) {
        #pragma unroll
        for (int i = 0; i < 4; ++i) {
            const int r = r0 + ty*4 + i;
            #pragma unroll
            for (int j = 0; j < 4; ++j) {
                const int n = n0 + tx*4 + j;
                E1[(size_t)r*256 + n] = fexp2(C_SCALE * (acc[i][j] + b1[n]));
            }
        }
    } else {
        #pragma unroll
        for (int i = 0; i < 4; ++i) {
            const int r = r0 + ty*4 + i;   // d index
            #pragma unroll
            for (int j = 0; j < 4; ++j) {
                const int n = n0 + tx*4 + j;  // gm index
                E2p[(size_t)(r >> 2)*8192 + (size_t)n*4 + (r & 3)] = fexp2(C_SCALE * acc[i][j]);
            }
        }
    }
}

// Fused: S = Wsum - 2*sum_d w[d]/(1+E1*E2), mask, softmax, single-pass PV.
// Grid 512 (= B*TX/4), block 1024 (16 waves). Block owns 4 x-rows.
// Thread t: tm = t&255 -> m in {tm, tm+256}; dq = t>>8 -> d-quarter (64 d).
__global__ __launch_bounds__(1024) void fused_tanh_attn(
    const float* __restrict__ E1,     // [B*TX, D]
    const float* __restrict__ E2p,    // packed [(d>>2)][gm][4]
    const float* __restrict__ memory, // [B, TM, D]
    const int*   __restrict__ mask,   // [B, TM]
    const float* __restrict__ wst,    // [D]
    float* __restrict__ out,          // [B*TX, D]
    float* __restrict__ Sout)         // [B*TX, TM]
{
    const float LOG2E = 1.4426950408889634f;
    const int t = threadIdx.x;
    // XCD-aware bijective swizzle (512 = 8*64)
    const int blk = (int)((blockIdx.x & 7) * 64 + (blockIdx.x >> 3));
    const int b = blk >> 7;                // 128 blocks per batch
    const int x0 = (blk & 127) * 4;
    const int wave = t >> 6, lane = t & 63;
    const int tm = t & 255;
    const int dq = t >> 8;                 // 0..3

    __shared__ float i1R[4][D_MODEL];       // 4 KB
    __shared__ float wsh[D_MODEL];          // 1 KB
    __shared__ float Pq[4][4][TM];          // 32 KB  [dq][row][m]
    __shared__ float mneg[TM];              // 2 KB
    __shared__ float oacc[4][D_MODEL];      // 4 KB (atomic-accumulated PV)
    __shared__ float wpart[4];
    __shared__ float smax[4][4], ssum[4][4];

    // stage E1 rows, zero oacc, wst, mask
    {
        const float* i1g = E1 + ((size_t)b * TX + x0) * D_MODEL;
        i1R[t >> 8][t & 255] = i1g[(size_t)(t >> 8) * D_MODEL + (t & 255)];
    }
    ((float*)oacc)[t] = 0.f;
    if (t < 256) wsh[t] = wst[t];
    if (t < 512) mneg[t] = mask[b*TM + t] ? 0.f : -__builtin_inff();

    // Wsum = sum(wst): waves 0..3
    if (wave < 4) {
        float s = wst[wave * 64 + lane];
        #pragma unroll
        for (int off = 32; off > 0; off >>= 1) s += __shfl_xor(s, off);
        if (lane == 0) wpart[wave] = s;
    }

    // first E2 group loads (both m streams, this thread's d-quarter)
    const int g0 = dq * 16;
    const float* e2ptrA = E2p + ((size_t)b * TM + tm) * 4;
    const float* e2ptrB = e2ptrA + 1024;   // m + 256
    float4 e2a = *(const float4*)(e2ptrA + (size_t)g0 * 8192);
    float4 e2b = *(const float4*)(e2ptrB + (size_t)g0 * 8192);

    __syncthreads();
    const float Wsum = wpart[0] + wpart[1] + wpart[2] + wpart[3];

    // main loop: 16 groups of 4 d; 1-deep prefetch; one rcp per quad
    float accA[4] = {}, accB[4] = {};
    #pragma unroll 2
    for (int gi = 0; gi < 16; ++gi) {
        const int g = g0 + gi;
        float4 e2an = e2a, e2bn = e2b;
        if (gi < 15) {
            e2an = *(const float4*)(e2ptrA + (size_t)(g + 1) * 8192);
            e2bn = *(const float4*)(e2ptrB + (size_t)(g + 1) * 8192);
        }
        float4 w4 = *(const float4*)&wsh[g * 4];
        #pragma unroll
        for (int r = 0; r < 4; ++r) {
            float4 a = *(const float4*)&i1R[r][g * 4];
            accA[r] = quad(a, e2a, w4, accA[r]);
            accB[r] = quad(a, e2b, w4, accB[r]);
        }
        e2a = e2an; e2b = e2bn;
    }

    // write d-quarter partials (disjoint)
    #pragma unroll
    for (int r = 0; r < 4; ++r) {
        Pq[dq][r][tm]       = accA[r];
        Pq[dq][r][tm + 256] = accB[r];
    }
    __syncthreads();

    // 16-wave softmax: wave -> (row r = wave&3, quarter q = wave>>2), 2 values/lane
    {
        const int r = wave & 3, qq = wave >> 2;
        const int m = qq * 128 + lane * 2;
        float2 a0 = *(const float2*)&Pq[0][r][m];
        float2 a1 = *(const float2*)&Pq[1][r][m];
        float2 a2 = *(const float2*)&Pq[2][r][m];
        float2 a3 = *(const float2*)&Pq[3][r][m];
        float2 mn = *(const float2*)&mneg[m];
        float v0 = Wsum - 2.f * ((a0.x + a1.x) + (a2.x + a3.x)) + mn.x;
        float v1 = Wsum - 2.f * ((a0.y + a1.y) + (a2.y + a3.y)) + mn.y;
        float mx = fmaxf(v0, v1);
        #pragma unroll
        for (int off = 32; off > 0; off >>= 1) mx = fmaxf(mx, __shfl_xor(mx, off));
        float e0 = fexp2((v0 - mx) * LOG2E);
        float e1 = fexp2((v1 - mx) * LOG2E);
        float sum = e0 + e1;
        #pragma unroll
        for (int off = 32; off > 0; off >>= 1) sum += __shfl_xor(sum, off);
        if (lane == 0) { smax[r][qq] = mx; ssum[r][qq] = sum; }
        __syncthreads();
        const float m0 = smax[r][0], m1 = smax[r][1], m2 = smax[r][2], m3 = smax[r][3];
        const float mg = fmaxf(fmaxf(m0, m1), fmaxf(m2, m3));
        const float tot = ssum[r][0] * fexp2((m0 - mg) * LOG2E)
                        + ssum[r][1] * fexp2((m1 - mg) * LOG2E)
                        + ssum[r][2] * fexp2((m2 - mg) * LOG2E)
                        + ssum[r][3] * fexp2((m3 - mg) * LOG2E);
        const float fac = fexp2((mx - mg) * LOG2E) * frcp(tot);
        float2 p = {e0 * fac, e1 * fac};
        *(float2*)&Pq[0][r][m] = p;   // final P lives in Pq[0]
        *(float2*)(Sout + ((size_t)b*TX + x0 + r) * TM + m) = p;
    }
    __syncthreads();

    // PV: wave owns m in [wave*32, wave*32+32); memory read once per block.
    // Partials accumulated straight into LDS via ds_add_f32 (no cross-barrier liveness).
    {
        const int m0 = wave * 32;
        const float* memp = memory + ((size_t)b * TM + m0) * D_MODEL + lane * 4;
        float4 o0 = {0,0,0,0}, o1 = {0,0,0,0}, o2 = {0,0,0,0}, o3 = {0,0,0,0};
        #pragma unroll
        for (int c = 0; c < 8; ++c) {
            float4 p0 = *(const float4*)&Pq[0][0][m0 + c*4];
            float4 p1 = *(const float4*)&Pq[0][1][m0 + c*4];
            float4 p2 = *(const float4*)&Pq[0][2][m0 + c*4];
            float4 p3 = *(const float4*)&Pq[0][3][m0 + c*4];
            #pragma unroll
            for (int j = 0; j < 4; ++j) {
                float4 mv = *(const float4*)(memp + (size_t)(c*4 + j) * D_MODEL);
                const float q0 = (j==0)?p0.x:(j==1)?p0.y:(j==2)?p0.z:p0.w;
                const float q1 = (j==0)?p1.x:(j==1)?p1.y:(j==2)?p1.z:p1.w;
                const float q2 = (j==0)?p2.x:(j==1)?p2.y:(j==2)?p2.z:p2.w;
                const float q3 = (j==0)?p3.x:(j==1)?p3.y:(j==2)?p3.z:p3.w;
                o0.x = fmaf(q0, mv.x, o0.x); o0.y = fmaf(q0, mv.y, o0.y);
                o0.z = fmaf(q0, mv.z, o0.z); o0.w = fmaf(q0, mv.w, o0.w);
                o1.x = fmaf(q1, mv.x, o1.x); o1.y = fmaf(q1, mv.y, o1.y);
                o1.z = fmaf(q1, mv.z, o1.z); o1.w = fmaf(q1, mv.w, o1.w);
                o2.x = fmaf(q2, mv.x, o2.x); o2.y = fmaf(q2, mv.y, o2.y);
                o2.z = fmaf(q2, mv.z, o2.z); o2.w = fmaf(q2, mv.w, o2.w);
                o3.x = fmaf(q3, mv.x, o3.x); o3.y = fmaf(q3, mv.y, o3.y);
                o3.z = fmaf(q3, mv.z, o3.z); o3.w = fmaf(q3, mv.w, o3.w);
            }
        }
        const int d0 = lane * 4;
        atomicAdd(&oacc[0][d0+0], o0.x); atomicAdd(&oacc[0][d0+1], o0.y);
        atomicAdd(&oacc[0][d0+2], o0.z); atomicAdd(&oacc[0][d0+3], o0.w);
        atomicAdd(&oacc[1][d0+0], o1.x); atomicAdd(&oacc[1][d0+1], o1.y);
        atomicAdd(&oacc[1][d0+2], o1.z); atomicAdd(&oacc[1][d0+3], o1.w);
        atomicAdd(&oacc[2][d0+0], o2.x); atomicAdd(&oacc[2][d0+1], o2.y);
        atomicAdd(&oacc[2][d0+2], o2.z); atomicAdd(&oacc[2][d0+3], o2.w);
        atomicAdd(&oacc[3][d0+0], o3.x); atomicAdd(&oacc[3][d0+1], o3.y);
        atomicAdd(&oacc[3][d0+2], o3.z); atomicAdd(&oacc[3][d0+3], o3.w);
    }
    __syncthreads();

    // write out: 1024 outputs, 1 per thread
    {
        const int row = t >> 8, d0 = t & 255;
        out[((size_t)b*TX + x0 + row) * D_MODEL + d0] = oacc[row][d0];
    }
}

extern "C" void kernel_launch(void* const* d_in, const int* in_sizes, int n_in,
                              void* d_out, int out_size, void* d_ws, size_t ws_size,
                              hipStream_t stream) {
    const float* x    = (const float*)d_in[0];
    const float* mem  = (const float*)d_in[1];
    const int*   mask = (const int*)d_in[2];
    const float* w1   = (const float*)d_in[3];
    const float* b1   = (const float*)d_in[4];
    const float* w2   = (const float*)d_in[5];
    const float* wst  = (const float*)d_in[6];

    float* out  = (float*)d_out;                  // [4*512*256]
    float* Sout = out + 4 * 512 * 256;            // [4*512*512]
    float* E1   = (float*)d_ws;                   // 524288 floats (2 MB), [2048][256]
    float* E2p  = E1 + 4 * 512 * 256;             // 524288 floats (2 MB), packed

    dim3 gg(256, 1, 2);
    gemm_exp2<<<gg, 128, 0, stream>>>(x, mem, w1, b1, w2, E1, E2p);
    fused_tanh_attn<<<512, 1024, 0, stream>>>(E1, E2p, mem, mask, wst, out, Sout);
}

// Round 15
// 58.896 us; speedup vs baseline: 1.7401x; 1.7401x over previous
//
#include <hip/hip_runtime.h>

#define D_MODEL 256
#define TX 512
#define TM 512

__device__ __forceinline__ float fexp2(float x) { return __builtin_amdgcn_exp2f(x); }
__device__ __forceinline__ float frcp(float x)  { return __builtin_amdgcn_rcpf(x); }

// acc += sum_{i=0..3} w[i]/(1+a[i]*e[i])  with ONE v_rcp_f32 (exact algebra).
__device__ __forceinline__ float quad(float4 a, float4 e, float4 w, float acc) {
    float p1 = fmaf(a.x, e.x, 1.f);
    float p2 = fmaf(a.y, e.y, 1.f);
    float p3 = fmaf(a.z, e.z, 1.f);
    float p4 = fmaf(a.w, e.w, 1.f);
    float p12 = p1 * p2;
    float p34 = p3 * p4;
    float q12 = fmaf(w.x, p2, w.y * p1);
    float q34 = fmaf(w.z, p4, w.w * p3);
    float N   = fmaf(q12, p34, q34 * p12);
    float D   = p12 * p34;
    return fmaf(N, frcp(D), acc);
}

// Two NT-GEMMs; 32x64 tiles, 128-thread blocks, double-buffered LDS.
//  z=0: E1 [2048][256] = exp2(c*(x · w1^T + b1));  bid -> r0=(bid&63)*32, n0=(bid>>6)*64
//  z=1: E2p packed     = exp2(c*(w2 · mem^T));     bid -> r0=(bid&7)*32,  n0=(bid>>3)*64
// Grid (256, 1, 2), block 128.
__global__ __launch_bounds__(128) void gemm_exp2(
    const float* __restrict__ x,   const float* __restrict__ mem,
    const float* __restrict__ w1,  const float* __restrict__ b1,
    const float* __restrict__ w2,
    float* __restrict__ E1, float* __restrict__ E2p)
{
    const float C_SCALE = 2.8853900817779268f; // 2*log2(e)
    const int bid = (int)blockIdx.x;
    const float* A; const float* W;
    int r0, n0;
    if (blockIdx.z == 0) { A = x;  W = w1; r0 = (bid & 63) * 32; n0 = (bid >> 6) * 64; }
    else                 { A = w2; W = mem; r0 = (bid & 7) * 32;  n0 = (bid >> 3) * 64; }

    __shared__ float As[2][16][36];
    __shared__ float Ws[2][16][68];
    const int tid = threadIdx.x;
    const int tx = tid & 15, ty = tid >> 4;     // 16 col-groups x 8 row-groups
    const int rl = tid >> 2, g = tid & 3;       // staging: 32 rows x 4 k-groups
    float acc[4][4] = {};
    const float* Ap  = A + (size_t)(r0 + rl) * 256 + g * 4;
    const float* Wp0 = W + (size_t)(n0 + rl) * 256 + g * 4;
    const float* Wp1 = W + (size_t)(n0 + 32 + rl) * 256 + g * 4;

    {   // prologue: stage k0 = 0 into buffer 0
        float4 a4 = *(const float4*)Ap;
        float4 w4 = *(const float4*)Wp0;
        float4 w5 = *(const float4*)Wp1;
        As[0][g*4+0][rl] = a4.x; As[0][g*4+1][rl] = a4.y;
        As[0][g*4+2][rl] = a4.z; As[0][g*4+3][rl] = a4.w;
        Ws[0][g*4+0][rl] = w4.x; Ws[0][g*4+1][rl] = w4.y;
        Ws[0][g*4+2][rl] = w4.z; Ws[0][g*4+3][rl] = w4.w;
        Ws[0][g*4+0][rl+32] = w5.x; Ws[0][g*4+1][rl+32] = w5.y;
        Ws[0][g*4+2][rl+32] = w5.z; Ws[0][g*4+3][rl+32] = w5.w;
    }
    __syncthreads();

    for (int k0 = 0; k0 < 16; ++k0) {
        const int cur = k0 & 1;
        float4 an, wn, vn;
        if (k0 < 15) {
            an = *(const float4*)(Ap  + (k0 + 1) * 16);
            wn = *(const float4*)(Wp0 + (k0 + 1) * 16);
            vn = *(const float4*)(Wp1 + (k0 + 1) * 16);
        }
        #pragma unroll
        for (int kk = 0; kk < 16; ++kk) {
            float4 av = *(const float4*)&As[cur][kk][ty*4];
            float4 wv = *(const float4*)&Ws[cur][kk][tx*4];
            float a_[4] = {av.x, av.y, av.z, av.w};
            float w_[4] = {wv.x, wv.y, wv.z, wv.w};
            #pragma unroll
            for (int i = 0; i < 4; ++i)
                #pragma unroll
                for (int j = 0; j < 4; ++j)
                    acc[i][j] = fmaf(a_[i], w_[j], acc[i][j]);
        }
        if (k0 < 15) {
            const int nxt = cur ^ 1;
            As[nxt][g*4+0][rl] = an.x; As[nxt][g*4+1][rl] = an.y;
            As[nxt][g*4+2][rl] = an.z; As[nxt][g*4+3][rl] = an.w;
            Ws[nxt][g*4+0][rl] = wn.x; Ws[nxt][g*4+1][rl] = wn.y;
            Ws[nxt][g*4+2][rl] = wn.z; Ws[nxt][g*4+3][rl] = wn.w;
            Ws[nxt][g*4+0][rl+32] = vn.x; Ws[nxt][g*4+1][rl+32] = vn.y;
            Ws[nxt][g*4+2][rl+32] = vn.z; Ws[nxt][g*4+3][rl+32] = vn.w;
            __syncthreads();
        }
    }

    if (blockIdx.z == 0) {
        #pragma unroll
        for (int i = 0; i < 4; ++i) {
            const int r = r0 + ty*4 + i;
            #pragma unroll
            for (int j = 0; j < 4; ++j) {
                const int n = n0 + tx*4 + j;
                E1[(size_t)r*256 + n] = fexp2(C_SCALE * (acc[i][j] + b1[n]));
            }
        }
    } else {
        #pragma unroll
        for (int i = 0; i < 4; ++i) {
            const int r = r0 + ty*4 + i;   // d index
            #pragma unroll
            for (int j = 0; j < 4; ++j) {
                const int n = n0 + tx*4 + j;  // gm index
                E2p[(size_t)(r >> 2)*8192 + (size_t)n*4 + (r & 3)] = fexp2(C_SCALE * acc[i][j]);
            }
        }
    }
}

// Fused: S = Wsum - 2*sum_d w[d]/(1+E1*E2), mask, 8-wave softmax, single-pass PV.
// Grid 512 (= B*TX/4), block 512 (8 waves). Block owns 4 x-rows.
// Thread t: tm = t&255 -> m in {tm, tm+256}; dh = t>>8 -> d-half (128 d).
// This is the r11 structure (measured 44 us) + 8-wave softmax.
__global__ __launch_bounds__(512) void fused_tanh_attn(
    const float* __restrict__ E1,     // [B*TX, D]
    const float* __restrict__ E2p,    // packed [(d>>2)][gm][4]
    const float* __restrict__ memory, // [B, TM, D]
    const int*   __restrict__ mask,   // [B, TM]
    const float* __restrict__ wst,    // [D]
    float* __restrict__ out,          // [B*TX, D]
    float* __restrict__ Sout)         // [B*TX, TM]
{
    const float LOG2E = 1.4426950408889634f;
    const int t = threadIdx.x;
    // XCD-aware bijective swizzle (512 = 8*64)
    const int blk = (int)((blockIdx.x & 7) * 64 + (blockIdx.x >> 3));
    const int b = blk >> 7;                // 128 blocks per batch
    const int x0 = (blk & 127) * 4;
    const int wave = t >> 6, lane = t & 63;
    const int tm = t & 255;
    const int dh = t >> 8;                 // 0 or 1

    __shared__ float i1R[4][D_MODEL];       // 4 KB
    __shared__ float wsh[D_MODEL];          // 1 KB
    __shared__ float P[4][TM];              // 8 KB
    __shared__ float mneg[TM];              // 2 KB
    __shared__ float opart[8][4][D_MODEL];  // 32 KB
    __shared__ float wpart[8];
    __shared__ float smax[4][2], ssum[4][2];

    // stage E1 rows, wst, mask
    {
        const float* i1g = E1 + ((size_t)b * TX + x0) * D_MODEL;
        const int row = t >> 7, col2 = (t & 127) * 2;
        float2 v = *(const float2*)(i1g + (size_t)row * D_MODEL + col2);
        *(float2*)&i1R[row][col2] = v;
    }
    if (t < 256) wsh[t] = wst[t];
    mneg[t] = mask[b*TM + t] ? 0.f : -__builtin_inff();

    // Wsum = sum(wst)
    {
        float s = (t < 256) ? wst[t] : 0.f;
        #pragma unroll
        for (int off = 32; off > 0; off >>= 1) s += __shfl_xor(s, off);
        if (lane == 0) wpart[wave] = s;
    }

    // first E2 group loads (both m streams, this thread's d-half)
    const int g0 = dh * 32;
    const float* e2ptrA = E2p + ((size_t)b * TM + tm) * 4;
    const float* e2ptrB = e2ptrA + 1024;   // m + 256
    float4 e2a = *(const float4*)(e2ptrA + (size_t)g0 * 8192);
    float4 e2b = *(const float4*)(e2ptrB + (size_t)g0 * 8192);

    __syncthreads();
    const float Wsum = wpart[0] + wpart[1] + wpart[2] + wpart[3]
                     + wpart[4] + wpart[5] + wpart[6] + wpart[7];

    // main loop: 32 groups of 4 d; 1-deep prefetch; one rcp per quad
    float accA[4] = {}, accB[4] = {};
    #pragma unroll 2
    for (int gi = 0; gi < 32; ++gi) {
        const int g = g0 + gi;
        float4 e2an = e2a, e2bn = e2b;
        if (gi < 31) {
            e2an = *(const float4*)(e2ptrA + (size_t)(g + 1) * 8192);
            e2bn = *(const float4*)(e2ptrB + (size_t)(g + 1) * 8192);
        }
        float4 w4 = *(const float4*)&wsh[g * 4];
        #pragma unroll
        for (int r = 0; r < 4; ++r) {
            float4 a = *(const float4*)&i1R[r][g * 4];
            accA[r] = quad(a, e2a, w4, accA[r]);
            accB[r] = quad(a, e2b, w4, accB[r]);
        }
        e2a = e2an; e2b = e2bn;
    }

    // combine d-halves through P, apply Wsum/mask
    if (dh == 0) {
        #pragma unroll
        for (int r = 0; r < 4; ++r) {
            P[r][tm]       = accA[r];
            P[r][tm + 256] = accB[r];
        }
    }
    __syncthreads();
    if (dh == 1) {
        const float mnA = mneg[tm], mnB = mneg[tm + 256];
        #pragma unroll
        for (int r = 0; r < 4; ++r) {
            P[r][tm]       = Wsum - 2.f * (P[r][tm]       + accA[r]) + mnA;
            P[r][tm + 256] = Wsum - 2.f * (P[r][tm + 256] + accB[r]) + mnB;
        }
    }
    __syncthreads();

    // 8-wave softmax: wave -> (row r = wave&3, half h = wave>>2), 4 values/lane
    {
        const int r = wave & 3, h = wave >> 2;
        const int base = h * 256 + lane * 4;
        float4 v4 = *(const float4*)&P[r][base];
        float v0 = v4.x, v1 = v4.y, v2 = v4.z, v3 = v4.w;
        float mx = fmaxf(fmaxf(v0, v1), fmaxf(v2, v3));
        #pragma unroll
        for (int off = 32; off > 0; off >>= 1) mx = fmaxf(mx, __shfl_xor(mx, off));
        float e0 = fexp2((v0 - mx) * LOG2E);
        float e1 = fexp2((v1 - mx) * LOG2E);
        float e2 = fexp2((v2 - mx) * LOG2E);
        float e3 = fexp2((v3 - mx) * LOG2E);
        float sum = (e0 + e1) + (e2 + e3);
        #pragma unroll
        for (int off = 32; off > 0; off >>= 1) sum += __shfl_xor(sum, off);
        if (lane == 0) { smax[r][h] = mx; ssum[r][h] = sum; }
        __syncthreads();
        const float m0 = smax[r][0], m1 = smax[r][1];
        const float mg = fmaxf(m0, m1);
        const float tot = ssum[r][0] * fexp2((m0 - mg) * LOG2E)
                        + ssum[r][1] * fexp2((m1 - mg) * LOG2E);
        const float fac = fexp2((mx - mg) * LOG2E) * frcp(tot);
        float4 p = {e0 * fac, e1 * fac, e2 * fac, e3 * fac};
        *(float4*)&P[r][base] = p;
        *(float4*)(Sout + ((size_t)b*TX + x0 + r) * TM + base) = p;
    }
    __syncthreads();

    // PV: wave owns m in [wave*64, wave*64+64); all 4 rows per load.
    // memory read exactly once per block; P read as broadcast float4.
    {
        const int m0 = wave * 64;
        const float* memp = memory + ((size_t)b * TM + m0) * D_MODEL + lane * 4;
        float4 o0 = {0,0,0,0}, o1 = {0,0,0,0}, o2 = {0,0,0,0}, o3 = {0,0,0,0};
        for (int c = 0; c < 16; ++c) {
            float4 p0 = *(const float4*)&P[0][m0 + c*4];
            float4 p1 = *(const float4*)&P[1][m0 + c*4];
            float4 p2 = *(const float4*)&P[2][m0 + c*4];
            float4 p3 = *(const float4*)&P[3][m0 + c*4];
            #pragma unroll
            for (int j = 0; j < 4; ++j) {
                float4 mv = *(const float4*)(memp + (size_t)(c*4 + j) * D_MODEL);
                const float q0 = (j==0)?p0.x:(j==1)?p0.y:(j==2)?p0.z:p0.w;
                const float q1 = (j==0)?p1.x:(j==1)?p1.y:(j==2)?p1.z:p1.w;
                const float q2 = (j==0)?p2.x:(j==1)?p2.y:(j==2)?p2.z:p2.w;
                const float q3 = (j==0)?p3.x:(j==1)?p3.y:(j==2)?p3.z:p3.w;
                o0.x = fmaf(q0, mv.x, o0.x); o0.y = fmaf(q0, mv.y, o0.y);
                o0.z = fmaf(q0, mv.z, o0.z); o0.w = fmaf(q0, mv.w, o0.w);
                o1.x = fmaf(q1, mv.x, o1.x); o1.y = fmaf(q1, mv.y, o1.y);
                o1.z = fmaf(q1, mv.z, o1.z); o1.w = fmaf(q1, mv.w, o1.w);
                o2.x = fmaf(q2, mv.x, o2.x); o2.y = fmaf(q2, mv.y, o2.y);
                o2.z = fmaf(q2, mv.z, o2.z); o2.w = fmaf(q2, mv.w, o2.w);
                o3.x = fmaf(q3, mv.x, o3.x); o3.y = fmaf(q3, mv.y, o3.y);
                o3.z = fmaf(q3, mv.z, o3.z); o3.w = fmaf(q3, mv.w, o3.w);
            }
        }
        *(float4*)&opart[wave][0][lane*4] = o0;
        *(float4*)&opart[wave][1][lane*4] = o1;
        *(float4*)&opart[wave][2][lane*4] = o2;
        *(float4*)&opart[wave][3][lane*4] = o3;
    }
    __syncthreads();

    // combine 8 wave-partials: 1024 outputs, 2 per thread
    {
        #pragma unroll
        for (int k = 0; k < 2; ++k) {
            const int idx = t + k * 512;
            const int row = idx >> 8, d0 = idx & 255;
            float s = 0.f;
            #pragma unroll
            for (int w = 0; w < 8; ++w) s += opart[w][row][d0];
            out[((size_t)b*TX + x0 + row) * D_MODEL + d0] = s;
        }
    }
}

extern "C" void kernel_launch(void* const* d_in, const int* in_sizes, int n_in,
                              void* d_out, int out_size, void* d_ws, size_t ws_size,
                              hipStream_t stream) {
    const float* x    = (const float*)d_in[0];
    const float* mem  = (const float*)d_in[1];
    const int*   mask = (const int*)d_in[2];
    const float* w1   = (const float*)d_in[3];
    const float* b1   = (const float*)d_in[4];
    const float* w2   = (const float*)d_in[5];
    const float* wst  = (const float*)d_in[6];

    float* out  = (float*)d_out;                  // [4*512*256]
    float* Sout = out + 4 * 512 * 256;            // [4*512*512]
    float* E1   = (float*)d_ws;                   // 524288 floats (2 MB), [2048][256]
    float* E2p  = E1 + 4 * 512 * 256;             // 524288 floats (2 MB), packed

    dim3 gg(256, 1, 2);
    gemm_exp2<<<gg, 128, 0, stream>>>(x, mem, w1, b1, w2, E1, E2p);
    fused_tanh_attn<<<512, 512, 0, stream>>>(E1, E2p, mem, mask, wst, out, Sout);
}

// Round 16
// 57.042 us; speedup vs baseline: 1.7967x; 1.0325x over previous
//
#include <hip/hip_runtime.h>

#define D_MODEL 256
#define TX 512
#define TM 512

__device__ __forceinline__ float fexp2(float x) { return __builtin_amdgcn_exp2f(x); }
__device__ __forceinline__ float frcp(float x)  { return __builtin_amdgcn_rcpf(x); }

// acc += sum_{i=0..3} w[i]/(1+a[i]*e[i])  with ONE v_rcp_f32 (exact algebra).
__device__ __forceinline__ float quad(float4 a, float4 e, float4 w, float acc) {
    float p1 = fmaf(a.x, e.x, 1.f);
    float p2 = fmaf(a.y, e.y, 1.f);
    float p3 = fmaf(a.z, e.z, 1.f);
    float p4 = fmaf(a.w, e.w, 1.f);
    float p12 = p1 * p2;
    float p34 = p3 * p4;
    float q12 = fmaf(w.x, p2, w.y * p1);
    float q34 = fmaf(w.z, p4, w.w * p3);
    float N   = fmaf(q12, p34, q34 * p12);
    float D   = p12 * p34;
    return fmaf(N, frcp(D), acc);
}

// Two NT-GEMMs; 64x64 tiles, 512-thread blocks (8 waves), double-buffered LDS.
// 2 blocks/CU = 16 waves/CU (vs 4 in all prior GEMM configs).
//  z=0: E1 [2048][256] = exp2(c*(x · w1^T + b1));  r0=(bid&31)*64, n0=(bid>>5)*64
//  z=1: E2p packed     = exp2(c*(w2 · mem^T));     r0=(bid>>5)*64, n0=(bid&31)*64
// Grid (128, 1, 2), block 512. Thread: tx=t&15 (4 cols), ty=t>>4 (2 rows).
__global__ __launch_bounds__(512) void gemm_exp2(
    const float* __restrict__ x,   const float* __restrict__ mem,
    const float* __restrict__ w1,  const float* __restrict__ b1,
    const float* __restrict__ w2,
    float* __restrict__ E1, float* __restrict__ E2p)
{
    const float C_SCALE = 2.8853900817779268f; // 2*log2(e)
    const int bid = (int)blockIdx.x;
    const float* A; const float* W;
    int r0, n0;
    if (blockIdx.z == 0) { A = x;  W = w1; r0 = (bid & 31) * 64; n0 = (bid >> 5) * 64; }
    else                 { A = w2; W = mem; r0 = (bid >> 5) * 64; n0 = (bid & 31) * 64; }

    __shared__ float As[2][16][68];
    __shared__ float Ws[2][16][68];
    const int t = threadIdx.x;
    const int tx = t & 15, ty = t >> 4;         // outputs: rows r0+ty*2+{0,1}, cols n0+tx*4+{0..3}
    const int half = t >> 8;                    // 0: stage A, 1: stage W
    const int st = t & 255;
    const int rl = st >> 2, g = st & 3;         // 64 rows x 4 k-groups
    float acc[2][4] = {};
    const float* Sp = (half == 0 ? A + (size_t)(r0 + rl) * 256
                                 : W + (size_t)(n0 + rl) * 256) + g * 4;

    {   // prologue: stage k0 = 0 into buffer 0
        float4 v = *(const float4*)Sp;
        float (*dst)[16][68] = (half == 0) ? &As[0] : &Ws[0];
        (*dst)[g*4+0][rl] = v.x; (*dst)[g*4+1][rl] = v.y;
        (*dst)[g*4+2][rl] = v.z; (*dst)[g*4+3][rl] = v.w;
    }
    __syncthreads();

    for (int k0 = 0; k0 < 16; ++k0) {
        const int cur = k0 & 1;
        float4 nv;
        if (k0 < 15) nv = *(const float4*)(Sp + (k0 + 1) * 16);
        #pragma unroll
        for (int kk = 0; kk < 16; ++kk) {
            float2 av = *(const float2*)&As[cur][kk][ty*2];
            float4 wv = *(const float4*)&Ws[cur][kk][tx*4];
            acc[0][0] = fmaf(av.x, wv.x, acc[0][0]);
            acc[0][1] = fmaf(av.x, wv.y, acc[0][1]);
            acc[0][2] = fmaf(av.x, wv.z, acc[0][2]);
            acc[0][3] = fmaf(av.x, wv.w, acc[0][3]);
            acc[1][0] = fmaf(av.y, wv.x, acc[1][0]);
            acc[1][1] = fmaf(av.y, wv.y, acc[1][1]);
            acc[1][2] = fmaf(av.y, wv.z, acc[1][2]);
            acc[1][3] = fmaf(av.y, wv.w, acc[1][3]);
        }
        if (k0 < 15) {
            const int nxt = cur ^ 1;
            float (*dst)[16][68] = (half == 0) ? &As[nxt] : &Ws[nxt];
            (*dst)[g*4+0][rl] = nv.x; (*dst)[g*4+1][rl] = nv.y;
            (*dst)[g*4+2][rl] = nv.z; (*dst)[g*4+3][rl] = nv.w;
            __syncthreads();
        }
    }

    if (blockIdx.z == 0) {
        #pragma unroll
        for (int i = 0; i < 2; ++i) {
            const int r = r0 + ty*2 + i;
            #pragma unroll
            for (int j = 0; j < 4; ++j) {
                const int n = n0 + tx*4 + j;
                E1[(size_t)r*256 + n] = fexp2(C_SCALE * (acc[i][j] + b1[n]));
            }
        }
    } else {
        #pragma unroll
        for (int i = 0; i < 2; ++i) {
            const int r = r0 + ty*2 + i;   // d index
            #pragma unroll
            for (int j = 0; j < 4; ++j) {
                const int n = n0 + tx*4 + j;  // gm index
                E2p[(size_t)(r >> 2)*8192 + (size_t)n*4 + (r & 3)] = fexp2(C_SCALE * acc[i][j]);
            }
        }
    }
}

// Fused: S = Wsum - 2*sum_d w[d]/(1+E1*E2), mask, 8-wave softmax, single-pass PV.
// Grid 512 (= B*TX/4), block 512 (8 waves). Block owns 4 x-rows.
// Thread t: tm = t&255 -> m in {tm, tm+256}; dh = t>>8 -> d-half (128 d).
// r11 structure (measured 44 us) + 8-wave softmax.
__global__ __launch_bounds__(512) void fused_tanh_attn(
    const float* __restrict__ E1,     // [B*TX, D]
    const float* __restrict__ E2p,    // packed [(d>>2)][gm][4]
    const float* __restrict__ memory, // [B, TM, D]
    const int*   __restrict__ mask,   // [B, TM]
    const float* __restrict__ wst,    // [D]
    float* __restrict__ out,          // [B*TX, D]
    float* __restrict__ Sout)         // [B*TX, TM]
{
    const float LOG2E = 1.4426950408889634f;
    const int t = threadIdx.x;
    // XCD-aware bijective swizzle (512 = 8*64)
    const int blk = (int)((blockIdx.x & 7) * 64 + (blockIdx.x >> 3));
    const int b = blk >> 7;                // 128 blocks per batch
    const int x0 = (blk & 127) * 4;
    const int wave = t >> 6, lane = t & 63;
    const int tm = t & 255;
    const int dh = t >> 8;                 // 0 or 1

    __shared__ float i1R[4][D_MODEL];       // 4 KB
    __shared__ float wsh[D_MODEL];          // 1 KB
    __shared__ float P[4][TM];              // 8 KB
    __shared__ float mneg[TM];              // 2 KB
    __shared__ float opart[8][4][D_MODEL];  // 32 KB
    __shared__ float wpart[8];
    __shared__ float smax[4][2], ssum[4][2];

    // stage E1 rows, wst, mask
    {
        const float* i1g = E1 + ((size_t)b * TX + x0) * D_MODEL;
        const int row = t >> 7, col2 = (t & 127) * 2;
        float2 v = *(const float2*)(i1g + (size_t)row * D_MODEL + col2);
        *(float2*)&i1R[row][col2] = v;
    }
    if (t < 256) wsh[t] = wst[t];
    mneg[t] = mask[b*TM + t] ? 0.f : -__builtin_inff();

    // Wsum = sum(wst)
    {
        float s = (t < 256) ? wst[t] : 0.f;
        #pragma unroll
        for (int off = 32; off > 0; off >>= 1) s += __shfl_xor(s, off);
        if (lane == 0) wpart[wave] = s;
    }

    // first E2 group loads (both m streams, this thread's d-half)
    const int g0 = dh * 32;
    const float* e2ptrA = E2p + ((size_t)b * TM + tm) * 4;
    const float* e2ptrB = e2ptrA + 1024;   // m + 256
    float4 e2a = *(const float4*)(e2ptrA + (size_t)g0 * 8192);
    float4 e2b = *(const float4*)(e2ptrB + (size_t)g0 * 8192);

    __syncthreads();
    const float Wsum = wpart[0] + wpart[1] + wpart[2] + wpart[3]
                     + wpart[4] + wpart[5] + wpart[6] + wpart[7];

    // main loop: 32 groups of 4 d; 1-deep prefetch; one rcp per quad
    float accA[4] = {}, accB[4] = {};
    #pragma unroll 2
    for (int gi = 0; gi < 32; ++gi) {
        const int g = g0 + gi;
        float4 e2an = e2a, e2bn = e2b;
        if (gi < 31) {
            e2an = *(const float4*)(e2ptrA + (size_t)(g + 1) * 8192);
            e2bn = *(const float4*)(e2ptrB + (size_t)(g + 1) * 8192);
        }
        float4 w4 = *(const float4*)&wsh[g * 4];
        #pragma unroll
        for (int r = 0; r < 4; ++r) {
            float4 a = *(const float4*)&i1R[r][g * 4];
            accA[r] = quad(a, e2a, w4, accA[r]);
            accB[r] = quad(a, e2b, w4, accB[r]);
        }
        e2a = e2an; e2b = e2bn;
    }

    // combine d-halves through P, apply Wsum/mask
    if (dh == 0) {
        #pragma unroll
        for (int r = 0; r < 4; ++r) {
            P[r][tm]       = accA[r];
            P[r][tm + 256] = accB[r];
        }
    }
    __syncthreads();
    if (dh == 1) {
        const float mnA = mneg[tm], mnB = mneg[tm + 256];
        #pragma unroll
        for (int r = 0; r < 4; ++r) {
            P[r][tm]       = Wsum - 2.f * (P[r][tm]       + accA[r]) + mnA;
            P[r][tm + 256] = Wsum - 2.f * (P[r][tm + 256] + accB[r]) + mnB;
        }
    }
    __syncthreads();

    // 8-wave softmax: wave -> (row r = wave&3, half h = wave>>2), 4 values/lane
    {
        const int r = wave & 3, h = wave >> 2;
        const int base = h * 256 + lane * 4;
        float4 v4 = *(const float4*)&P[r][base];
        float v0 = v4.x, v1 = v4.y, v2 = v4.z, v3 = v4.w;
        float mx = fmaxf(fmaxf(v0, v1), fmaxf(v2, v3));
        #pragma unroll
        for (int off = 32; off > 0; off >>= 1) mx = fmaxf(mx, __shfl_xor(mx, off));
        float e0 = fexp2((v0 - mx) * LOG2E);
        float e1 = fexp2((v1 - mx) * LOG2E);
        float e2 = fexp2((v2 - mx) * LOG2E);
        float e3 = fexp2((v3 - mx) * LOG2E);
        float sum = (e0 + e1) + (e2 + e3);
        #pragma unroll
        for (int off = 32; off > 0; off >>= 1) sum += __shfl_xor(sum, off);
        if (lane == 0) { smax[r][h] = mx; ssum[r][h] = sum; }
        __syncthreads();
        const float m0 = smax[r][0], m1 = smax[r][1];
        const float mg = fmaxf(m0, m1);
        const float tot = ssum[r][0] * fexp2((m0 - mg) * LOG2E)
                        + ssum[r][1] * fexp2((m1 - mg) * LOG2E);
        const float fac = fexp2((mx - mg) * LOG2E) * frcp(tot);
        float4 p = {e0 * fac, e1 * fac, e2 * fac, e3 * fac};
        *(float4*)&P[r][base] = p;
        *(float4*)(Sout + ((size_t)b*TX + x0 + r) * TM + base) = p;
    }
    __syncthreads();

    // PV: wave owns m in [wave*64, wave*64+64); all 4 rows per load.
    // memory read exactly once per block; P read as broadcast float4.
    {
        const int m0 = wave * 64;
        const float* memp = memory + ((size_t)b * TM + m0) * D_MODEL + lane * 4;
        float4 o0 = {0,0,0,0}, o1 = {0,0,0,0}, o2 = {0,0,0,0}, o3 = {0,0,0,0};
        for (int c = 0; c < 16; ++c) {
            float4 p0 = *(const float4*)&P[0][m0 + c*4];
            float4 p1 = *(const float4*)&P[1][m0 + c*4];
            float4 p2 = *(const float4*)&P[2][m0 + c*4];
            float4 p3 = *(const float4*)&P[3][m0 + c*4];
            #pragma unroll
            for (int j = 0; j < 4; ++j) {
                float4 mv = *(const float4*)(memp + (size_t)(c*4 + j) * D_MODEL);
                const float q0 = (j==0)?p0.x:(j==1)?p0.y:(j==2)?p0.z:p0.w;
                const float q1 = (j==0)?p1.x:(j==1)?p1.y:(j==2)?p1.z:p1.w;
                const float q2 = (j==0)?p2.x:(j==1)?p2.y:(j==2)?p2.z:p2.w;
                const float q3 = (j==0)?p3.x:(j==1)?p3.y:(j==2)?p3.z:p3.w;
                o0.x = fmaf(q0, mv.x, o0.x); o0.y = fmaf(q0, mv.y, o0.y);
                o0.z = fmaf(q0, mv.z, o0.z); o0.w = fmaf(q0, mv.w, o0.w);
                o1.x = fmaf(q1, mv.x, o1.x); o1.y = fmaf(q1, mv.y, o1.y);
                o1.z = fmaf(q1, mv.z, o1.z); o1.w = fmaf(q1, mv.w, o1.w);
                o2.x = fmaf(q2, mv.x, o2.x); o2.y = fmaf(q2, mv.y, o2.y);
                o2.z = fmaf(q2, mv.z, o2.z); o2.w = fmaf(q2, mv.w, o2.w);
                o3.x = fmaf(q3, mv.x, o3.x); o3.y = fmaf(q3, mv.y, o3.y);
                o3.z = fmaf(q3, mv.z, o3.z); o3.w = fmaf(q3, mv.w, o3.w);
            }
        }
        *(float4*)&opart[wave][0][lane*4] = o0;
        *(float4*)&opart[wave][1][lane*4] = o1;
        *(float4*)&opart[wave][2][lane*4] = o2;
        *(float4*)&opart[wave][3][lane*4] = o3;
    }
    __syncthreads();

    // combine 8 wave-partials: 1024 outputs, 2 per thread
    {
        #pragma unroll
        for (int k = 0; k < 2; ++k) {
            const int idx = t + k * 512;
            const int row = idx >> 8, d0 = idx & 255;
            float s = 0.f;
            #pragma unroll
            for (int w = 0; w < 8; ++w) s += opart[w][row][d0];
            out[((size_t)b*TX + x0 + row) * D_MODEL + d0] = s;
        }
    }
}

extern "C" void kernel_launch(void* const* d_in, const int* in_sizes, int n_in,
                              void* d_out, int out_size, void* d_ws, size_t ws_size,
                              hipStream_t stream) {
    const float* x    = (const float*)d_in[0];
    const float* mem  = (const float*)d_in[1];
    const int*   mask = (const int*)d_in[2];
    const float* w1   = (const float*)d_in[3];
    const float* b1   = (const float*)d_in[4];
    const float* w2   = (const float*)d_in[5];
    const float* wst  = (const float*)d_in[6];

    float* out  = (float*)d_out;                  // [4*512*256]
    float* Sout = out + 4 * 512 * 256;            // [4*512*512]
    float* E1   = (float*)d_ws;                   // 524288 floats (2 MB), [2048][256]
    float* E2p  = E1 + 4 * 512 * 256;             // 524288 floats (2 MB), packed

    dim3 gg(128, 1, 2);
    gemm_exp2<<<gg, 512, 0, stream>>>(x, mem, w1, b1, w2, E1, E2p);
    fused_tanh_attn<<<512, 512, 0, stream>>>(E1, E2p, mem, mask, wst, out, Sout);
}